// Round 13
// baseline (313.864 us; speedup 1.0000x reference)
//
#include <hip/hip_runtime.h>
#include <math.h>

#define NBATCH 4096
#define NH2 21
#define NK 77
#define NC 35
#define NIJ 441
#define Y_SIZE 33957
#define M_SIZE 5929
#define NPAIR 231              // upper-triangular (i<=j) pairs of 21
#define BLK 512                // contract block threads (8 waves)
#define NPB 16                 // R20: 256 blocks = 1/CU
#define GRID_B (NBATCH / NPB)  // 256 blocks
#define EIGT 640               // bisect block: 10 waves (verified 9-section code)
#define LDS_K 72               // R19: D/P row stride in shorts (2-way = free)

// workspace layout (d_ws):
//  priv (ws_size >= ~18.2MB): GRID_B private slots + 160 tridiag d/e + 256
//    vol partials. Plain stores everywhere -> NO ws memset.
//  fallback: NSLOT=16 shared slots (atomicAdd, memset) + 160 + 256.
#define NSLOT 16
#define SLOT_STRIDE 17792      // NPAIR*NK=17787 padded
#define WS2OFF_FB  (NSLOT * SLOT_STRIDE)
#define WS2OFF_PRV (GRID_B * SLOT_STRIDE)
#define WS_NEED_PRV ((size_t)(WS2OFF_PRV + 160 + GRID_B) * 4)

#define SZ_OMEGA  (NBATCH * NH2 * NH2)   // 1,806,336
#define SZ_PHI    (NBATCH * NK * NC)     // 11,038,720
#define SZ_METRIC (NBATCH * 7 * 7)       // 200,704

// ---------------- compile-time wedge structure constants ----------------
// C[a,b,c] nonzero iff pair_a, pair_b, triple_c partition {0..6}; value = perm
// sign. Exactly 6 (a,b) terms per c. MUST be a constexpr LOCAL in each kernel
// (round-3 finding). C[a,b,c]=C[b,a,c] => S symmetric in (i,j): only i<=j pairs.
// R5: never cap VGPRs below live set (spill -> 5x).
// R12: shfl == ds_bpermute ~120-150cy LDS hop; DPP adds ~5cy.
// R16: tridiag schedule PINNED (R15/R17/R18 restructures all failed).
// R18/R19 LESSON: rocprof per-dispatch times for the 1-wave tridiag are
//   clock-state artifacts across sessions. TRUST dur_us ONLY cross-round.
// R20 (-28us): contract atomics are COUNT-bound. R21 (-7us): privatized
//   per-block slots, plain stores. R22: shorten the serial dispatch chain —
//   vol fused into contract prologue, d_out memset removed (every out element
//   fully written; VSUM via 256 ws partials reduced in finalize). 7 -> 5
//   dispatches. (R12 bench attempt hit an infra failure; this is a resubmit.)
// R7: LDS strides sharing a factor with the bank-group period -> conflicts.
struct WTab {
  int a[NC][6];
  int b[NC][6];
  int sg[NC][6];
};

constexpr WTab make_wtab() {
  WTab W{};
  int p0[21] = {}, p1[21] = {};
  int idx = 0;
  for (int x = 0; x < 7; ++x)
    for (int y = x + 1; y < 7; ++y) { p0[idx] = x; p1[idx] = y; ++idx; }
  int t0[35] = {}, t1[35] = {}, t2[35] = {};
  idx = 0;
  for (int x = 0; x < 7; ++x)
    for (int y = x + 1; y < 7; ++y)
      for (int z = y + 1; z < 7; ++z) { t0[idx] = x; t1[idx] = y; t2[idx] = z; ++idx; }
  int cnt[35] = {};
  for (int a = 0; a < 21; ++a)
    for (int b = 0; b < 21; ++b) {
      int pa0 = p0[a], pa1 = p1[a], pb0 = p0[b], pb1 = p1[b];
      if (pa0 == pb0 || pa0 == pb1 || pa1 == pb0 || pa1 == pb1) continue;
      bool used[7] = {};
      used[pa0] = true; used[pa1] = true; used[pb0] = true; used[pb1] = true;
      int tr[3] = {}; int k = 0;
      for (int x = 0; x < 7; ++x) if (!used[x]) tr[k++] = x;
      int c = -1;
      for (int cc = 0; cc < 35; ++cc)
        if (t0[cc] == tr[0] && t1[cc] == tr[1] && t2[cc] == tr[2]) { c = cc; break; }
      int perm[7] = {pa0, pa1, pb0, pb1, tr[0], tr[1], tr[2]};
      int inv = 0;
      for (int i = 0; i < 7; ++i)
        for (int j = i + 1; j < 7; ++j)
          if (perm[i] > perm[j]) ++inv;
      W.a[c][cnt[c]] = a; W.b[c][cnt[c]] = b; W.sg[c][cnt[c]] = (inv & 1) ? -1 : 1;
      ++cnt[c];
    }
  return W;
}

__device__ __forceinline__ int trioff(int i) { return 21 * i - (i * (i - 1)) / 2; }

// fp32 -> bf16 (RNE), returns low 16 bits
__device__ __forceinline__ unsigned f2bf(float x) {
  union { float f; unsigned u; } v; v.f = x;
  return ((v.u + 0x7FFFu + ((v.u >> 16) & 1u)) >> 16) & 0xFFFFu;
}

typedef float f32x4 __attribute__((ext_vector_type(4)));
typedef float f32x2 __attribute__((ext_vector_type(2)));
typedef short s16x8 __attribute__((ext_vector_type(8)));

// packed fp32 FMA (VOP3P, gfx90a+): d = a*b + c per 32-bit half. NOT volatile.
__device__ __forceinline__ f32x2 pk_fma(f32x2 a, f32x2 b, f32x2 c) {
  f32x2 d;
  asm("v_pk_fma_f32 %0, %1, %2, %3" : "=v"(d) : "v"(a), "v"(b), "v"(c));
  return d;
}

// ---------------- DPP wave reductions (R12): VALU-latency, no LDS pipe -------
template <int CTRL>
__device__ __forceinline__ float dppadd(float x) {
  union { float f; int i; } u, r;
  u.f = x;
  r.i = __builtin_amdgcn_update_dpp(0, u.i, CTRL, 0xF, 0xF, true);
  return x + r.f;
}
// sum over each aligned group of 8 lanes; result in ALL 8 lanes of the group
__device__ __forceinline__ float oct_sum(float x) {
  x = dppadd<0xB1>(x);    // quad_perm(1,0,3,2)  : + xor1
  x = dppadd<0x4E>(x);    // quad_perm(2,3,0,1)  : + xor2
  x = dppadd<0x141>(x);   // row_half_mirror     : + other quad of 8
  return x;
}
// sum over all 64 lanes; result valid in lane 63
__device__ __forceinline__ float wave_sum(float x) {
  x = dppadd<0xB1>(x);
  x = dppadd<0x4E>(x);
  x = dppadd<0x141>(x);
  x = dppadd<0x140>(x);   // row_mirror
  x = dppadd<0x142>(x);   // row_bcast15
  x = dppadd<0x143>(x);   // row_bcast31
  return x;
}
__device__ __forceinline__ float readlane63(float x) {
  union { float f; int i; } u; u.f = x;
  union { int i; float f; } r;
  r.i = __builtin_amdgcn_readlane(u.i, 63);
  return r.f;
}
__device__ __forceinline__ float readlane0(float x) {
  union { float f; int i; } u; u.f = x;
  union { int i; float f; } r;
  r.i = __builtin_amdgcn_readfirstlane(u.i);
  return r.f;
}
__device__ __forceinline__ float readlaneN(float x, int lane) {
  union { float f; int i; } u; u.f = x;
  union { int i; float f; } r;
  r.i = __builtin_amdgcn_readlane(u.i, lane);
  return r.f;
}

// ---------------- kernel B: MFMA contract (R22: fused vol, private slots) -----
__global__ __launch_bounds__(BLK) void contract_kernel(const float* __restrict__ omega,
                                                       const float* __restrict__ Phi,
                                                       const float* __restrict__ metric,
                                                       float* __restrict__ wsS,
                                                       float* __restrict__ vsp,
                                                       const int priv) {
  constexpr WTab W = make_wtab();
  __shared__ __align__(16) short ldsD[256 * LDS_K];  // D rows, stride 72 bf16
  __shared__ __align__(16) short ldsP[80 * LDS_K];   // PW^T rows [q][k]
  __shared__ __align__(16) float ldsO[NH2 * 28];     // omega rows, stride 28 fp32
  __shared__ float ldsVol[NPB];

  const int t = threadIdx.x;
  const int lane = t & 63;
  const int wv = t >> 6;
  const int quad = lane >> 4;
  const int col = lane & 15;
  const int n0 = blockIdx.x * NPB;

  for (int f = t; f < 256 * (LDS_K / 2); f += BLK) ((int*)ldsD)[f] = 0;
  for (int f = t; f < 80 * (LDS_K / 2); f += BLK) ((int*)ldsP)[f] = 0;

  // R22 prologue: lanes 0..15 compute vol for the block's 16 samples
  // (7x7 double LU, partial pivot — identical arithmetic to old vol_kernel).
  if (t < NPB) {
    const int n = n0 + t;
    double a[7][7];
#pragma unroll
    for (int r = 0; r < 7; ++r)
#pragma unroll
      for (int c = 0; c < 7; ++c) a[r][c] = (double)metric[n * 49 + r * 7 + c];
    double det = 1.0;
#pragma unroll
    for (int k = 0; k < 7; ++k) {
#pragma unroll
      for (int r = k + 1; r < 7; ++r) {
        bool sw = fabs(a[r][k]) > fabs(a[k][k]);
#pragma unroll
        for (int c = k; c < 7; ++c) {
          double u = a[k][c], v = a[r][c];
          a[k][c] = sw ? v : u;
          a[r][c] = sw ? u : v;
        }
      }
      det *= a[k][k];
      double inv = (a[k][k] != 0.0) ? 1.0 / a[k][k] : 0.0;
#pragma unroll
      for (int r = k + 1; r < 7; ++r) {
        double f = a[r][k] * inv;
#pragma unroll
        for (int c = k + 1; c < 7; ++c) a[r][c] -= f * a[k][c];
      }
    }
    ldsVol[t] = (float)sqrt(fabs(det));
  }
  __syncthreads();
  if (t == 0) {                       // block volsum partial (plain store)
    float s = 0.0f;
#pragma unroll
    for (int i = 0; i < NPB; ++i) s += ldsVol[i];
    vsp[blockIdx.x] = s;
  }

  const bool roleA = (t < NPAIR);
  const bool roleB = (t >= 256) && (t < 256 + NPAIR);
  int pi = 0, pj = 0;
  {
    const int p = roleA ? t : (roleB ? (t - 256) : 0);
    int i = 0;
    while (i < 20 && trioff(i + 1) <= p) ++i;
    pi = i;
    pj = p - trioff(i) + i;
  }

  float rA = 0.0f, rB[6], rvn;
  {
    const float* om = omega + n0 * 441;
    const float* ph = Phi + n0 * 2695;
    if (t < 441) rA = om[t];
#pragma unroll
    for (int j = 0; j < 6; ++j) {
      const int e = t + j * BLK;
      rB[j] = (e < 2695) ? ph[e] : 0.0f;
    }
    rvn = ldsVol[0];
  }

  f32x4 acc[2][5];
#pragma unroll
  for (int mi = 0; mi < 2; ++mi)
#pragma unroll
    for (int nt = 0; nt < 5; ++nt) acc[mi][nt] = (f32x4){0.f, 0.f, 0.f, 0.f};

  for (int it = 0; it < NPB; ++it) {
    __syncthreads();

    if (t < 441) ldsO[(t / 21) * 28 + (t % 21)] = rA;
    {
      const float vn = rvn;
#pragma unroll
      for (int j = 0; j < 6; ++j) {
        const int e = t + j * BLK;
        if (e < 2695) {
          const int q = e / 35, c = e % 35;
          ldsP[q * LDS_K + c] = (short)f2bf(vn * rB[j]);
        }
      }
    }
    __syncthreads();

    if (it + 1 < NPB) {
      const int n1 = n0 + it + 1;
      const float* om2 = omega + n1 * 441;
      const float* ph2 = Phi + n1 * 2695;
      if (t < 441) rA = om2[t];
#pragma unroll
      for (int j = 0; j < 6; ++j) {
        const int e = t + j * BLK;
        if (e < 2695) rB[j] = ph2[e];
      }
      rvn = ldsVol[it + 1];
    }

    if (roleA || roleB) {
      float wi[21], wj[21];
      const float* oi = ldsO + pi * 28;
      const float* oj = ldsO + pj * 28;
#pragma unroll
      for (int a = 0; a < 20; a += 4) {
        float4 v = *(const float4*)(oi + a);
        wi[a] = v.x; wi[a + 1] = v.y; wi[a + 2] = v.z; wi[a + 3] = v.w;
        float4 u = *(const float4*)(oj + a);
        wj[a] = u.x; wj[a + 1] = u.y; wj[a + 2] = u.z; wj[a + 3] = u.w;
      }
      wi[20] = oi[20]; wj[20] = oj[20];

      if (roleA) {
        float d[18];
#pragma unroll
        for (int c = 0; c < 18; ++c) {
          float dd = 0.0f;
#pragma unroll
          for (int u = 0; u < 6; ++u)
            dd = fmaf((W.sg[c][u] > 0) ? wi[W.a[c][u]] : -wi[W.a[c][u]], wj[W.b[c][u]], dd);
          d[c] = dd;
        }
        int* Drow = (int*)ldsD + t * (LDS_K / 2);
#pragma unroll
        for (int k2 = 0; k2 < 9; ++k2)
          Drow[k2] = (int)(f2bf(d[2 * k2]) | (f2bf(d[2 * k2 + 1]) << 16));
      } else {
        float d[17];
#pragma unroll
        for (int c = 18; c < 35; ++c) {
          float dd = 0.0f;
#pragma unroll
          for (int u = 0; u < 6; ++u)
            dd = fmaf((W.sg[c][u] > 0) ? wi[W.a[c][u]] : -wi[W.a[c][u]], wj[W.b[c][u]], dd);
          d[c - 18] = dd;
        }
        int* Drow = (int*)ldsD + (t - 256) * (LDS_K / 2);
#pragma unroll
        for (int k2 = 0; k2 < 8; ++k2)
          Drow[9 + k2] = (int)(f2bf(d[2 * k2]) | (f2bf(d[2 * k2 + 1]) << 16));
        Drow[17] = (int)f2bf(d[16]);
      }
    }
    __syncthreads();

#pragma unroll
    for (int s = 0; s < 2; ++s) {
      const int kof = s * 32 + quad * 8;
      s16x8 a0 = *(const s16x8*)(ldsD + ((wv * 2 + 0) * 16 + col) * LDS_K + kof);
      s16x8 a1 = *(const s16x8*)(ldsD + ((wv * 2 + 1) * 16 + col) * LDS_K + kof);
      s16x8 b[5];
#pragma unroll
      for (int nt = 0; nt < 5; ++nt)
        b[nt] = *(const s16x8*)(ldsP + (nt * 16 + col) * LDS_K + kof);
#pragma unroll
      for (int nt = 0; nt < 5; ++nt) {
        acc[0][nt] = __builtin_amdgcn_mfma_f32_16x16x32_bf16(a0, b[nt], acc[0][nt], 0, 0, 0);
        acc[1][nt] = __builtin_amdgcn_mfma_f32_16x16x32_bf16(a1, b[nt], acc[1][nt], 0, 0, 0);
      }
    }
  }

  // private slot -> plain stores; fallback: 16 shared slots + atomics.
  if (priv) {
    float* slot = wsS + (size_t)blockIdx.x * SLOT_STRIDE;
#pragma unroll
    for (int mi = 0; mi < 2; ++mi) {
      const int mt = wv * 2 + mi;
#pragma unroll
      for (int r = 0; r < 4; ++r) {
        const int m = mt * 16 + quad * 4 + r;
        if (m < NPAIR) {
#pragma unroll
          for (int nt = 0; nt < 5; ++nt) {
            const int q = nt * 16 + col;
            if (q < 77) slot[m * NK + q] = acc[mi][nt][r];
          }
        }
      }
    }
  } else {
    float* slot = wsS + (size_t)(blockIdx.x & (NSLOT - 1)) * SLOT_STRIDE;
#pragma unroll
    for (int mi = 0; mi < 2; ++mi) {
      const int mt = wv * 2 + mi;
#pragma unroll
      for (int r = 0; r < 4; ++r) {
        const int m = mt * 16 + quad * 4 + r;
        if (m < NPAIR) {
#pragma unroll
          for (int nt = 0; nt < 5; ++nt) {
            const int q = nt * 16 + col;
            if (q < 77) atomicAdd(&slot[m * NK + q], acc[mi][nt][r]);
          }
        }
      }
    }
  }
}

// ---------------- kernel C1: finalize Y (R22: cooperative VSUM) ---------------
__global__ __launch_bounds__(256) void finalize_y(const float* __restrict__ wsS,
                                                  const float* __restrict__ vsp,
                                                  float* __restrict__ out,
                                                  const int nslot) {
  __shared__ float vsh[4];
  const int tt = threadIdx.x;
  // cooperative VSUM: 256 threads load the 256 per-block vol partials
  {
    float pv = vsp[tt];                 // GRID_B == 256 == blockDim
    pv = wave_sum(pv);
    if ((tt & 63) == 63) vsh[tt >> 6] = pv;
  }
  __syncthreads();
  const float vsum = (vsh[0] + vsh[1]) + (vsh[2] + vsh[3]);

  const int e = blockIdx.x * 256 + tt;
  if (e >= NPAIR * NK) return;
  const int p = e / NK, k = e % NK;
  int i = 0;
  while (i < 20 && trioff(i + 1) <= p) ++i;
  const int j = p - trioff(i) + i;
  float v0 = 0.0f, v1 = 0.0f, v2 = 0.0f, v3 = 0.0f;
  const float* base = wsS + e;
  int s = 0;
#pragma unroll 1
  for (; s + 4 <= nslot; s += 4) {
    v0 += base[(size_t)(s + 0) * SLOT_STRIDE];
    v1 += base[(size_t)(s + 1) * SLOT_STRIDE];
    v2 += base[(size_t)(s + 2) * SLOT_STRIDE];
    v3 += base[(size_t)(s + 3) * SLOT_STRIDE];
  }
  for (; s < nslot; ++s) v0 += base[(size_t)s * SLOT_STRIDE];
  float v = (v0 + v1) + (v2 + v3);
  v *= 1.0f / vsum;
  out[(i * 21 + j) * NK + k] = v;
  if (j != i) out[(j * 21 + i) * NK + k] = -v;
}

// ---------------- kernel C2: M[k,l] = sum_ij Y_ij,k Y_ij,l (R14) ----------------
__global__ __launch_bounds__(EIGT) void gram_kernel(const float* __restrict__ Y,
                                                    float* __restrict__ Mout) {
  const int k = blockIdx.x;
  const int t = threadIdx.x;
  const int l = t >> 3, s = t & 7;
  float acc = 0.0f;
  if (l < NK) {
    for (int ij = s; ij < NIJ; ij += 8)
      acc = fmaf(Y[ij * NK + k], Y[ij * NK + l], acc);
  }
  acc = oct_sum(acc);
  if (s == 0 && l < NK) Mout[k * NK + l] = acc;
}

// ---------------- kernel D1: single-wave Householder tridiag (R16, PINNED) ----
// One wave, A[80x80] in VGPRs as f32x2 col-pairs: lane l=(br<<3)|bc owns rows
// [10br,+10) x col-pairs [5bc,+5). Zero barriers, zero LDS.
// R15/R17/R18 restructures all regressed — do not modify the schedule.
__global__ __launch_bounds__(64, 1) void tridiag_kernel(const float* __restrict__ Min,
                                                        float* __restrict__ ws2) {
  const int l = threadIdx.x;
  const int br = l >> 3, bc = l & 7;
  f32x2 A2[10][5];
#pragma unroll
  for (int r = 0; r < 10; ++r) {
    const int g = 10 * br + r;
#pragma unroll
    for (int c2 = 0; c2 < 5; ++c2) {
      const int gc0 = 10 * bc + 2 * c2;
      A2[r][c2][0] = (g < 77 && gc0 < 77) ? Min[g * 77 + gc0] : 0.0f;
      A2[r][c2][1] = (g < 77 && gc0 + 1 < 77) ? Min[g * 77 + gc0 + 1] : 0.0f;
    }
  }

  // prologue: broadcast row 0 (col-chunks from lane bc, row-chunks from lane br)
  float rc[10], rr[10];
#pragma unroll
  for (int c2 = 0; c2 < 5; ++c2) {
    rc[2 * c2]     = __shfl(A2[0][c2][0], bc, 64);
    rc[2 * c2 + 1] = __shfl(A2[0][c2][1], bc, 64);
    rr[2 * c2]     = __shfl(A2[0][c2][0], br, 64);
    rr[2 * c2 + 1] = __shfl(A2[0][c2][1], br, 64);
  }

#pragma unroll 1
  for (int kb = 0; kb < 8; ++kb) {
#pragma unroll
    for (int ko = 0; ko < 10; ++ko) {
      if (kb == 7 && ko >= 5) break;           // k stops at 74
      const int k = kb * 10 + ko;
      const int nko = (ko + 1) % 10;           // literal after unroll
      const int nkb = kb + (ko == 9 ? 1 : 0);
      const int nic = nkb * 8 + bc, nir = nkb * 8 + br;

      // sigma2 partials (br==0 lanes = oct 0) -> 3-hop oct_sum + readfirstlane
      float part = 0.0f;
      if (br == 0) {
#pragma unroll
        for (int c2 = 0; c2 < 5; ++c2) {
          const int gc0 = 10 * bc + 2 * c2;
          const float x0 = rc[2 * c2], xv = rc[2 * c2 + 1];
          part += (gc0 > k) ? x0 * x0 : 0.0f;
          part += (gc0 + 1 > k) ? xv * xv : 0.0f;
        }
      }
      part = oct_sum(part);
      const float sigma2 = readlane0(part);
      if (sigma2 < 1e-26f) {                   // uniform branch, rare
        if (l == 0) ws2[80 + k] = 0.0f;
#pragma unroll
        for (int c2 = 0; c2 < 5; ++c2) {       // still pipeline next bcast
          rc[2 * c2]     = __shfl(A2[nko][c2][0], nic, 64);
          rc[2 * c2 + 1] = __shfl(A2[nko][c2][1], nic, 64);
          rr[2 * c2]     = __shfl(A2[nko][c2][0], nir, 64);
          rr[2 * c2 + 1] = __shfl(A2[nko][c2][1], nir, 64);
        }
        continue;
      }
      // x1 = A[k][k+1]: col k+1 sits in rc[nko] of lanes with bc==nkb
      const float x1 = readlaneN(rc[nko], nkb);
      const float sigma = __builtin_amdgcn_sqrtf(sigma2);
      const float alpha = (x1 >= 0.0f) ? -sigma : sigma;
      const float beta = __builtin_amdgcn_rcpf(fmaf(-alpha, x1, sigma2));
      const float xha = x1 - alpha;
      if (l == 0) ws2[80 + k] = alpha;

      // v over own cols (from rc) and own rows (from rr) — both local
      f32x2 vc2[5];
      float vr[10];
#pragma unroll
      for (int c2 = 0; c2 < 5; ++c2) {
        const int gc0 = 10 * bc + 2 * c2;
        vc2[c2][0] = (gc0 > k) ? ((gc0 == k + 1) ? xha : rc[2 * c2]) : 0.0f;
        vc2[c2][1] = (gc0 + 1 > k) ? ((gc0 + 1 == k + 1) ? xha : rc[2 * c2 + 1]) : 0.0f;
        const int gr0 = 10 * br + 2 * c2;
        vr[2 * c2] = (gr0 > k) ? ((gr0 == k + 1) ? xha : rr[2 * c2]) : 0.0f;
        vr[2 * c2 + 1] = (gr0 + 1 > k) ? ((gr0 + 1 == k + 1) ? xha : rr[2 * c2 + 1]) : 0.0f;
      }

      // p = beta * A v (packed fma; rows independent)
      float p[10];
#pragma unroll
      for (int r = 0; r < 10; ++r) {
        f32x2 a = (f32x2){0.f, 0.f};
#pragma unroll
        for (int c2 = 0; c2 < 5; ++c2) a = pk_fma(A2[r][c2], vc2[c2], a);
        p[r] = a[0] + a[1];
      }
#pragma unroll
      for (int r = 0; r < 10; ++r) {
        p[r] = oct_sum(p[r]) * beta;
        p[r] = (10 * br + r > k) ? p[r] : 0.0f;
      }

      // prefetch p-by-columns NOW (hides under the K reduction)
      f32x2 pc2[5];
#pragma unroll
      for (int c2 = 0; c2 < 5; ++c2) {
        pc2[c2][0] = __shfl(p[2 * c2], 9 * bc, 64);
        pc2[c2][1] = __shfl(p[2 * c2 + 1], 9 * bc, 64);
      }

      // K = p . v (rows counted once: bc==0 lanes)
      float kp = 0.0f;
      if (bc == 0) {
#pragma unroll
        for (int r = 0; r < 10; ++r) kp = fmaf(p[r], vr[r], kp);
      }
      kp = wave_sum(kp);
      const float hb = 0.5f * beta * readlane63(kp);

      // w by rows (local); wc by cols LOCAL from prefetched pc
      float w[10];
#pragma unroll
      for (int r = 0; r < 10; ++r) w[r] = fmaf(-hb, vr[r], p[r]);
      const f32x2 mhb = (f32x2){-hb, -hb};
      f32x2 wc2[5];
#pragma unroll
      for (int c2 = 0; c2 < 5; ++c2) wc2[c2] = pk_fma(mhb, vc2[c2], pc2[c2]);

      // rank-2 update: pivot row nko FIRST, issue next broadcast, then rest
      {
        const f32x2 nv = (f32x2){-vr[nko], -vr[nko]};
        const f32x2 nw = (f32x2){-w[nko], -w[nko]};
#pragma unroll
        for (int c2 = 0; c2 < 5; ++c2)
          A2[nko][c2] = pk_fma(nv, wc2[c2], pk_fma(nw, vc2[c2], A2[nko][c2]));
      }
#pragma unroll
      for (int c2 = 0; c2 < 5; ++c2) {
        rc[2 * c2]     = __shfl(A2[nko][c2][0], nic, 64);
        rc[2 * c2 + 1] = __shfl(A2[nko][c2][1], nic, 64);
        rr[2 * c2]     = __shfl(A2[nko][c2][0], nir, 64);
        rr[2 * c2 + 1] = __shfl(A2[nko][c2][1], nir, 64);
      }
#pragma unroll
      for (int r = 0; r < 10; ++r) {
        if (r == nko) continue;
        const f32x2 nv = (f32x2){-vr[r], -vr[r]};
        const f32x2 nw = (f32x2){-w[r], -w[r]};
#pragma unroll
        for (int c2 = 0; c2 < 5; ++c2)
          A2[r][c2] = pk_fma(nv, wc2[c2], pk_fma(nw, vc2[c2], A2[r][c2]));
      }
    }
  }

  // gather tridiagonal: diag from lanes br==bc, last offdiag from lane 63
  if (br == bc) {
#pragma unroll
    for (int e = 0; e < 10; ++e)
      ws2[10 * br + e] = (e & 1) ? A2[e][e / 2][1] : A2[e][e / 2][0];
  }
  if (l == 63) ws2[80 + 75] = A2[6][2][1];     // A[76][75]
}

// ---------------- kernel D2: bisection (verified 9-section, 640 thr) ----------
__global__ __launch_bounds__(EIGT) void bisect_kernel(const float* __restrict__ ws2,
                                                      float* __restrict__ eout) {
  __shared__ float dsh[80], esh[80], e2sh[80];
  __shared__ float red[10], red2[10];
  const int t = threadIdx.x;
  const int lane = t & 63, wv = t >> 6;
  if (t < 80) {
    dsh[t] = ws2[t];
    esh[t] = (t < 76) ? ws2[80 + t] : 0.0f;
  }
  __syncthreads();
  if (t < 76) e2sh[t] = esh[t] * esh[t];

  // Gershgorin bounds (parallel reduce)
  float lo_ = 1e30f, hi_ = -1e30f;
  if (t < 77) {
    const float r = ((t > 0) ? fabsf(esh[t - 1]) : 0.0f) +
                    ((t < 76) ? fabsf(esh[t]) : 0.0f);
    lo_ = dsh[t] - r;
    hi_ = dsh[t] + r;
  }
#pragma unroll
  for (int off = 1; off < 64; off <<= 1) {
    lo_ = fminf(lo_, __shfl_xor(lo_, off, 64));
    hi_ = fmaxf(hi_, __shfl_xor(hi_, off, 64));
  }
  if (lane == 0) { red[wv] = lo_; red2[wv] = hi_; }
  __syncthreads();                          // also fences e2sh/dsh
  lo_ = red[0]; hi_ = red2[0];
#pragma unroll
  for (int u = 1; u < 10; ++u) { lo_ = fminf(lo_, red[u]); hi_ = fmaxf(hi_, red2[u]); }
  const float span = hi_ - lo_;
  const float glo = lo_ - 0.001f * span - 1e-6f;
  const float ghi = hi_ + 0.001f * span + 1e-6f;

  // 9-section search via Sturm count: 8 probe lanes per eigenvalue, 13 rounds
  {
    const int e = t >> 3;        // eigenvalue index 0..79 (77..79 inactive)
    const int s = t & 7;         // probe lane within oct
    const int g = (t & 63) >> 3; // oct group within wave
    float lo = glo, hi = ghi;
    for (int r = 0; r < 13; ++r) {
      const float step = (hi - lo) * (1.0f / 9.0f);
      const float x = fmaf(step, (float)(s + 1), lo);
      float q = dsh[0] - x;
      int cnt = (q < 0.0f);
#pragma unroll 4
      for (int i = 1; i < 77; ++i) {
        q = (fabsf(q) < 1e-30f) ? -1e-30f : q;
        q = dsh[i] - x - e2sh[i - 1] * __builtin_amdgcn_rcpf(q);
        cnt += (q < 0.0f);
      }
      const unsigned long long mask = __ballot(cnt > e);
      const int b = (int)((mask >> (g * 8)) & 0xFFull);
      const int z = b ? __builtin_ctz(b) : 8;   // probes with cnt<=e
      const float nlo = fmaf(step, (float)z, lo);
      hi = (z == 8) ? hi : fmaf(step, (float)(z + 1), lo);
      lo = nlo;
    }
    if (s == 0 && e < 77) eout[76 - e] = 0.5f * (lo + hi);  // descending
  }
}

// ---------------- launch ----------------
extern "C" void kernel_launch(void* const* d_in, const int* in_sizes, int n_in,
                              void* d_out, int out_size, void* d_ws, size_t ws_size,
                              hipStream_t stream) {
  const float* omega  = (const float*)d_in[0];
  const float* Phi    = (const float*)d_in[1];
  const float* metric = (const float*)d_in[2];
  for (int q = 0; q < n_in && q < 3; ++q) {
    if (in_sizes[q] == SZ_OMEGA)       omega  = (const float*)d_in[q];
    else if (in_sizes[q] == SZ_PHI)    Phi    = (const float*)d_in[q];
    else if (in_sizes[q] == SZ_METRIC) metric = (const float*)d_in[q];
  }

  float* out = (float*)d_out;
  float* ws  = (float*)d_ws;

  const int priv = (ws_size >= WS_NEED_PRV) ? 1 : 0;
  const int nslot = priv ? GRID_B : NSLOT;
  float* ws2 = ws + (priv ? WS2OFF_PRV : WS2OFF_FB);
  float* vsp = ws2 + 160;      // 256 vol partials

  // No d_out memset (R22): Y fully written by finalize (441x77), M by gram,
  // eig by bisect. ws memset only on the fallback atomic path.
  if (!priv)
    hipMemsetAsync(d_ws, 0, (size_t)WS2OFF_FB * sizeof(float), stream);

  hipLaunchKernelGGL(contract_kernel, dim3(GRID_B), dim3(BLK), 0, stream,
                     omega, Phi, metric, ws, vsp, priv);
  hipLaunchKernelGGL(finalize_y, dim3((NPAIR * NK + 255) / 256), dim3(256), 0, stream,
                     ws, vsp, out, nslot);
  hipLaunchKernelGGL(gram_kernel, dim3(NK), dim3(EIGT), 0, stream,
                     out, out + Y_SIZE);
  hipLaunchKernelGGL(tridiag_kernel, dim3(1), dim3(64), 0, stream,
                     out + Y_SIZE, ws2);
  hipLaunchKernelGGL(bisect_kernel, dim3(1), dim3(EIGT), 0, stream,
                     ws2, out + Y_SIZE + M_SIZE);
}